// Round 9
// baseline (223.534 us; speedup 1.0000x reference)
//
#include <hip/hip_runtime.h>
#include <hip/hip_bf16.h>
#include <math.h>

#define Bn 8
#define Sn 2048
#define Hn 768
#define NROW 4096          // B * N_SPANS
#define SPAN_DIM 2688
#define NBIG 1536          // fused GEMM N (768 type-t | 768 sens-pre)
#define NTYPE 18
#define NSENS 4
#define WPAD 24            // padded per-k weight row (shorts), 48 B

// merged pre-kernel block partition
#define NB_PROP 4096
#define NB_SPAN 4096
#define NB_T    2016       // per big transpose (84 x 24 tiles of 32x32)
#define NB_SM   156        // small-weight prep
#define NB_TOTAL (NB_PROP + NB_SPAN + 2 * NB_T + NB_SM)

typedef __attribute__((ext_vector_type(8))) short short8;
typedef __attribute__((ext_vector_type(4))) float floatx4;

__device__ __forceinline__ unsigned short f2bf(float x) {
    __hip_bfloat16 h = __float2bfloat16(x);
    return *reinterpret_cast<unsigned short*>(&h);
}

__device__ __forceinline__ float bfu(unsigned short u) {
    union { float f; unsigned int i; } v;
    v.i = ((unsigned int)u) << 16;
    return v.f;
}

__device__ __forceinline__ void glds16(const void* g, void* l) {
    __builtin_amdgcn_global_load_lds(
        (const __attribute__((address_space(1))) unsigned int*)g,
        (__attribute__((address_space(3))) unsigned int*)l, 16, 0, 0);
}

__device__ __forceinline__ float gelu_exact(float v) {
    return 0.5f * v * (1.f + erff(v * 0.70710678118654752f));
}

// ============ merged pre-kernel: proposal | span_rep | weight prep ============
__global__ __launch_bounds__(256) void pre_kernel(
    const float* __restrict__ hidden, const int* __restrict__ spans,
    const float* __restrict__ wemb,
    const float* __restrict__ Wp, const float* __restrict__ bp,
    const float* __restrict__ Wt1, const float* __restrict__ Ws1,
    const float* __restrict__ Wt2, const float* __restrict__ Ws2,
    float* __restrict__ out_prop, unsigned short* __restrict__ rep,
    unsigned short* __restrict__ WbigT,
    unsigned short* __restrict__ Wt2bf, unsigned short* __restrict__ Wtailbf,
    unsigned short* __restrict__ Ws2bf)
{
    __shared__ float tile[32][33];
    int id = blockIdx.x;
    int tid = threadIdx.x;

    if (id < NB_PROP) {
        int wave = tid >> 6, lane = tid & 63;
        int row = id * 4 + wave;
        const float4* h4 = (const float4*)(hidden + (size_t)row * Hn);
        float a0 = 0.f, a1 = 0.f, a2 = 0.f;
#pragma unroll
        for (int i = 0; i < 3; ++i) {
            int kc = i * 64 + lane;
            float4 h = h4[kc];
            const float* w = Wp + kc * 12;
            a0 += h.x * w[0] + h.y * w[3] + h.z * w[6] + h.w * w[9];
            a1 += h.x * w[1] + h.y * w[4] + h.z * w[7] + h.w * w[10];
            a2 += h.x * w[2] + h.y * w[5] + h.z * w[8] + h.w * w[11];
        }
#pragma unroll
        for (int off = 32; off; off >>= 1) {
            a0 += __shfl_xor(a0, off);
            a1 += __shfl_xor(a1, off);
            a2 += __shfl_xor(a2, off);
        }
        if (lane < 3) {
            float v = (lane == 0 ? a0 : (lane == 1 ? a1 : a2)) + bp[lane];
            out_prop[row * 3 + lane] = v;
        }
        return;
    }
    id -= NB_PROP;
    if (id < NB_SPAN) {
        if (tid >= 192) return;
        int n = id;
        int b = n >> 9;
        int s = spans[n * 2 + 0];
        int e = spans[n * 2 + 1];
        int w = e - s + 1;
        const float4* hb4 = (const float4*)(hidden + (size_t)b * Sn * Hn);
        unsigned short* r = rep + (size_t)n * SPAN_DIM;
        float inv_w = 1.0f / (float)w;

        float4 sv = hb4[(size_t)s * 192 + tid];
        float4 ev = hb4[(size_t)e * 192 + tid];
        float4 p0 = make_float4(0.f, 0.f, 0.f, 0.f), p1 = p0, p2 = p0, p3 = p0;
        int rr = s;
        for (; rr + 3 <= e; rr += 4) {
            float4 h0 = hb4[(size_t)(rr + 0) * 192 + tid];
            float4 h1 = hb4[(size_t)(rr + 1) * 192 + tid];
            float4 h2 = hb4[(size_t)(rr + 2) * 192 + tid];
            float4 h3 = hb4[(size_t)(rr + 3) * 192 + tid];
            p0.x += h0.x; p0.y += h0.y; p0.z += h0.z; p0.w += h0.w;
            p1.x += h1.x; p1.y += h1.y; p1.z += h1.z; p1.w += h1.w;
            p2.x += h2.x; p2.y += h2.y; p2.z += h2.z; p2.w += h2.w;
            p3.x += h3.x; p3.y += h3.y; p3.z += h3.z; p3.w += h3.w;
        }
        for (; rr <= e; ++rr) {
            float4 h = hb4[(size_t)rr * 192 + tid];
            p0.x += h.x; p0.y += h.y; p0.z += h.z; p0.w += h.w;
        }
        float4 pv;
        pv.x = ((p0.x + p1.x) + (p2.x + p3.x)) * inv_w;
        pv.y = ((p0.y + p1.y) + (p2.y + p3.y)) * inv_w;
        pv.z = ((p0.z + p1.z) + (p2.z + p3.z)) * inv_w;
        pv.w = ((p0.w + p1.w) + (p2.w + p3.w)) * inv_w;

        *(ushort4*)&r[tid * 4] =
            make_ushort4(f2bf(sv.x), f2bf(sv.y), f2bf(sv.z), f2bf(sv.w));
        *(ushort4*)&r[Hn + tid * 4] =
            make_ushort4(f2bf(ev.x), f2bf(ev.y), f2bf(ev.z), f2bf(ev.w));
        *(ushort4*)&r[2 * Hn + tid * 4] =
            make_ushort4(f2bf(pv.x), f2bf(pv.y), f2bf(pv.z), f2bf(pv.w));
        if (tid < 96) {
            int wi = w > 63 ? 63 : w;
            float4 wv = ((const float4*)wemb)[wi * 96 + tid];
            *(ushort4*)&r[3 * Hn + tid * 4] =
                make_ushort4(f2bf(wv.x), f2bf(wv.y), f2bf(wv.z), f2bf(wv.w));
        }
        return;
    }
    id -= NB_SPAN;
    if (id < 2 * NB_T) {
        int z = id / NB_T, l = id - z * NB_T;
        const float* W = (z == 0) ? Wt1 : Ws1;
        unsigned short* Wt = WbigT + (size_t)z * Hn * SPAN_DIM;
        int k0 = (l % 84) * 32, n0 = (l / 84) * 32;
        int tx = tid & 31, ty = tid >> 5;
#pragma unroll
        for (int i = 0; i < 32; i += 8)
            tile[ty + i][tx] = W[(size_t)(k0 + ty + i) * Hn + n0 + tx];
        __syncthreads();
#pragma unroll
        for (int i = 0; i < 32; i += 8)
            Wt[(size_t)(n0 + ty + i) * SPAN_DIM + k0 + tx] = f2bf(tile[tx][ty + i]);
        return;
    }
    id -= 2 * NB_T;
    {
        int idx = id * 256 + tid;
        const int N1 = Hn * WPAD;
        const int N2 = 2 * N1;
        const int N3 = N2 + Hn * NSENS;
        if (idx < N1) {
            int k = idx / WPAD, o = idx - k * WPAD;
            Wt2bf[idx] = (o < NTYPE) ? f2bf(Wt2[k * NTYPE + o]) : 0;
        } else if (idx < N2) {
            int j = idx - N1;
            int k = j / WPAD, o = j - k * WPAD;
            Wtailbf[j] = (o < NTYPE) ? f2bf(Ws1[(size_t)(SPAN_DIM + o) * Hn + k]) : 0;
        } else if (idx < N3) {
            int j = idx - N2;
            Ws2bf[j] = f2bf(Ws2[j]);
        }
    }
}

// ===== fused bf16 MFMA GEMM: BM=64, BN=128, BK=64, 2 waves each 64x64 =====
// grid 64x12 = 768 blocks of 128 threads (3 blocks/CU). Per wave per K=32:
// 8 ds_read_b128 : 16 MFMA (m97 ratio) with max fragment reuse (4,4).
__global__ __launch_bounds__(128, 2) void gemm_fused(
    const unsigned short* __restrict__ A,
    const unsigned short* __restrict__ Bt,
    const float* __restrict__ bt1, const float* __restrict__ bs1,
    unsigned short* __restrict__ obuf)
{
    const int BK = 64;
    __shared__ unsigned short As[64 * BK];    //  8 KB
    __shared__ unsigned short Bs[128 * BK];   // 16 KB

    int tid = threadIdx.x, wave = tid >> 6, lane = tid & 63;
    int m0 = blockIdx.x * 64, n0 = blockIdx.y * 128;

    int wc = wave * 64;             // wave's column half of the 128-wide B tile
    int fr = lane & 15;
    int fq = lane >> 4;             // 0..3: 16B chunk within a 32-k window

    // staging: chunk d, r=d>>3 (8 chunks per row), swizzled col c=(d&7)^(r&7)
    const unsigned short* gA[4];
#pragma unroll
    for (int j = 0; j < 4; ++j) {
        int d = tid + j * 128;      // 0..511 -> A rows 0..63
        int r = d >> 3, c = (d & 7) ^ (r & 7);
        gA[j] = A + (size_t)(m0 + r) * SPAN_DIM + c * 8;
    }
    const unsigned short* gB[8];
#pragma unroll
    for (int j = 0; j < 8; ++j) {
        int d = tid + j * 128;      // 0..1023 -> B rows 0..127
        int r = d >> 3, c = (d & 7) ^ (r & 7);
        gB[j] = Bt + (size_t)(n0 + r) * SPAN_DIM + c * 8;
    }
    int offA[4], offB[8];
#pragma unroll
    for (int j = 0; j < 4; ++j) offA[j] = j * 1024 + wave * 512;
#pragma unroll
    for (int j = 0; j < 8; ++j) offB[j] = j * 1024 + wave * 512;

    floatx4 acc[4][4] = {};

    for (int k0 = 0; k0 < SPAN_DIM; k0 += BK) {
        glds16(gA[0] + k0, &As[offA[0]]);
        glds16(gA[1] + k0, &As[offA[1]]);
        glds16(gA[2] + k0, &As[offA[2]]);
        glds16(gA[3] + k0, &As[offA[3]]);
        glds16(gB[0] + k0, &Bs[offB[0]]);
        glds16(gB[1] + k0, &Bs[offB[1]]);
        glds16(gB[2] + k0, &Bs[offB[2]]);
        glds16(gB[3] + k0, &Bs[offB[3]]);
        glds16(gB[4] + k0, &Bs[offB[4]]);
        glds16(gB[5] + k0, &Bs[offB[5]]);
        glds16(gB[6] + k0, &Bs[offB[6]]);
        glds16(gB[7] + k0, &Bs[offB[7]]);
        __syncthreads();

#pragma unroll
        for (int half = 0; half < 2; ++half) {
            int cb = half * 4 + fq;
            short8 af[4], bf[4];
#pragma unroll
            for (int i = 0; i < 4; ++i) {
                int r = i * 16 + fr;                 // A rows 0..63 (shared)
                af[i] = *(const short8*)&As[((r << 3) | (cb ^ (r & 7))) * 8];
            }
#pragma unroll
            for (int i = 0; i < 4; ++i) {
                int r = wc + i * 16 + fr;            // B rows, per-wave half
                bf[i] = *(const short8*)&Bs[((r << 3) | (cb ^ (r & 7))) * 8];
            }
#pragma unroll
            for (int mi = 0; mi < 4; ++mi)
#pragma unroll
                for (int ni = 0; ni < 4; ++ni)
                    acc[mi][ni] = __builtin_amdgcn_mfma_f32_16x16x32_bf16(
                        af[mi], bf[ni], acc[mi][ni], 0, 0, 0);
        }
        __syncthreads();
    }

    bool isT = (n0 < Hn);
    const float* bias = isT ? bt1 : (bs1 - Hn);
    int cr = (lane >> 4) * 4;
#pragma unroll
    for (int mi = 0; mi < 4; ++mi) {
#pragma unroll
        for (int ni = 0; ni < 4; ++ni) {
            int col = n0 + wc + ni * 16 + fr;
            float bv = bias[col];
#pragma unroll
            for (int r = 0; r < 4; ++r) {
                int row = m0 + mi * 16 + cr + r;
                float v = acc[mi][ni][r] + bv;
                if (isT) v = gelu_exact(v);
                obuf[(size_t)row * NBIG + col] = f2bf(v);
            }
        }
    }
}

// --- fused heads on bf16 obuf: lane owns ushort4 chunks (k = 4*(lane+i*64)+j) ---
__global__ __launch_bounds__(256) void heads_kernel(
    const unsigned short* __restrict__ obuf, const unsigned short* __restrict__ Wt2bf,
    const float* __restrict__ bt2, const unsigned short* __restrict__ Wtailbf,
    const unsigned short* __restrict__ Ws2bf, const float* __restrict__ bs2,
    float* __restrict__ out_type, float* __restrict__ out_sens)
{
    int wave = threadIdx.x >> 6, lane = threadIdx.x & 63;
    int row = blockIdx.x * 4 + wave;
    const ushort4* tr4 = (const ushort4*)(obuf + (size_t)row * NBIG);

    float acc[NTYPE] = {};
#pragma unroll
    for (int i = 0; i < 3; ++i) {
        ushort4 tc = tr4[lane + i * 64];
        float tv[4] = {bfu(tc.x), bfu(tc.y), bfu(tc.z), bfu(tc.w)};
#pragma unroll
        for (int j = 0; j < 4; ++j) {
            int k = (lane + i * 64) * 4 + j;
            const unsigned short* wp = Wt2bf + (size_t)k * WPAD;
            short8 w0 = *(const short8*)wp;
            short8 w1 = *(const short8*)(wp + 8);
            ushort4 w2 = *(const ushort4*)(wp + 16);
#pragma unroll
            for (int o = 0; o < 8; ++o) acc[o] += tv[j] * bfu((unsigned short)w0[o]);
#pragma unroll
            for (int o = 0; o < 8; ++o) acc[8 + o] += tv[j] * bfu((unsigned short)w1[o]);
            acc[16] += tv[j] * bfu(w2.x);
            acc[17] += tv[j] * bfu(w2.y);
        }
    }
#pragma unroll
    for (int o = 0; o < NTYPE; ++o)
#pragma unroll
        for (int off = 32; off; off >>= 1) acc[o] += __shfl_xor(acc[o], off);

    float mx = -1e30f;
#pragma unroll
    for (int o = 0; o < NTYPE; ++o) { acc[o] += bt2[o]; mx = fmaxf(mx, acc[o]); }
    {
        float lv = 0.f;
#pragma unroll
        for (int o = 0; o < NTYPE; ++o) lv = (lane == o) ? acc[o] : lv;
        if (lane < NTYPE) out_type[row * NTYPE + lane] = lv;
    }
    float pr[NTYPE], sum = 0.f;
#pragma unroll
    for (int o = 0; o < NTYPE; ++o) { pr[o] = expf(acc[o] - mx); sum += pr[o]; }
    float inv = 1.f / sum;
#pragma unroll
    for (int o = 0; o < NTYPE; ++o) pr[o] *= inv;

    const ushort4* sp4 = (const ushort4*)(obuf + (size_t)row * NBIG + Hn);
    float acc2[NSENS] = {};
#pragma unroll
    for (int i = 0; i < 3; ++i) {
        ushort4 sc = sp4[lane + i * 64];
        float sv[4] = {bfu(sc.x), bfu(sc.y), bfu(sc.z), bfu(sc.w)};
#pragma unroll
        for (int j = 0; j < 4; ++j) {
            int k = (lane + i * 64) * 4 + j;
            const unsigned short* wt = Wtailbf + (size_t)k * WPAD;
            short8 a0 = *(const short8*)wt;
            short8 a1 = *(const short8*)(wt + 8);
            ushort4 a2 = *(const ushort4*)(wt + 16);
            float tl = 0.f;
#pragma unroll
            for (int o = 0; o < 8; ++o) tl += pr[o] * bfu((unsigned short)a0[o]);
#pragma unroll
            for (int o = 0; o < 8; ++o) tl += pr[8 + o] * bfu((unsigned short)a1[o]);
            tl += pr[16] * bfu(a2.x) + pr[17] * bfu(a2.y);
            float v = gelu_exact(sv[j] + tl);
            ushort4 wv = *(const ushort4*)(Ws2bf + (size_t)k * NSENS);
            acc2[0] += v * bfu(wv.x);
            acc2[1] += v * bfu(wv.y);
            acc2[2] += v * bfu(wv.z);
            acc2[3] += v * bfu(wv.w);
        }
    }
#pragma unroll
    for (int o = 0; o < NSENS; ++o)
#pragma unroll
        for (int off = 32; off; off >>= 1) acc2[o] += __shfl_xor(acc2[o], off);
    {
        float lv = 0.f;
#pragma unroll
        for (int o = 0; o < NSENS; ++o) lv = (lane == o) ? (acc2[o] + bs2[o]) : lv;
        if (lane < NSENS) out_sens[row * NSENS + lane] = lv;
    }
}

extern "C" void kernel_launch(void* const* d_in, const int* in_sizes, int n_in,
                              void* d_out, int out_size, void* d_ws, size_t ws_size,
                              hipStream_t stream)
{
    const float* hidden = (const float*)d_in[0];
    const int*   spans  = (const int*)d_in[1];
    const float* wemb   = (const float*)d_in[2];
    const float* Wp     = (const float*)d_in[3];
    const float* bp     = (const float*)d_in[4];
    const float* Wt1    = (const float*)d_in[5];
    const float* bt1    = (const float*)d_in[6];
    const float* Wt2    = (const float*)d_in[7];
    const float* bt2    = (const float*)d_in[8];
    const float* Ws1    = (const float*)d_in[9];
    const float* bs1    = (const float*)d_in[10];
    const float* Ws2    = (const float*)d_in[11];
    const float* bs2    = (const float*)d_in[12];

    float* out      = (float*)d_out;
    float* out_prop = out;
    float* out_type = out + Bn * Sn * 3;
    float* out_sens = out_type + NROW * NTYPE;

    // workspace layout (all 16B-aligned)
    unsigned short* rep  = (unsigned short*)d_ws;                // [4096][2688] bf16
    unsigned short* obuf = rep + (size_t)NROW * SPAN_DIM;        // [4096][1536] bf16
    unsigned short* WbigT = obuf + (size_t)NROW * NBIG;          // [1536][2688] bf16
    unsigned short* Wt2bf   = WbigT + (size_t)NBIG * SPAN_DIM;   // [768][24] bf16
    unsigned short* Wtailbf = Wt2bf + Hn * WPAD;                 // [768][24] bf16
    unsigned short* Ws2bf   = Wtailbf + Hn * WPAD;               // [768][4]  bf16

    pre_kernel<<<NB_TOTAL, 256, 0, stream>>>(
        hidden, spans, wemb, Wp, bp, Wt1, Ws1, Wt2, Ws2,
        out_prop, rep, WbigT, Wt2bf, Wtailbf, Ws2bf);

    dim3 gg(NROW / 64, NBIG / 128);   // 64 x 12 = 768 blocks of 128 threads
    gemm_fused<<<gg, 128, 0, stream>>>(rep, WbigT, bt1, bs1, obuf);

    heads_kernel<<<NROW / 4, 256, 0, stream>>>(
        obuf, Wt2bf, bt2, Wtailbf, Ws2bf, bs2, out_type, out_sens);
}